// Round 1
// baseline (10058.479 us; speedup 1.0000x reference)
//
#include <hip/hip_runtime.h>
#include <hip/hip_bf16.h>

typedef __attribute__((ext_vector_type(8))) short short8;
typedef __attribute__((ext_vector_type(4))) float f32x4;
typedef __attribute__((ext_vector_type(4))) unsigned short us4;

#define T_ 1024
#define F_ 128
#define U_ 256
#define NU 1024  /* 4U */

__device__ __forceinline__ unsigned short f2bf(float f){
  unsigned u = __float_as_uint(f);
  u += 0x7FFFu + ((u >> 16) & 1u);
  return (unsigned short)(u >> 16);
}
__device__ __forceinline__ float bf2f(unsigned short s){
  return __uint_as_float(((unsigned)s) << 16);
}
__device__ __forceinline__ float sigm(float x){ return 1.0f/(1.0f + __expf(-x)); }
__device__ __forceinline__ float tanh_f(float x){
  x = fminf(20.0f, fmaxf(-20.0f, x));
  float e = __expf(2.0f*x);
  return (e - 1.0f)/(e + 1.0f);
}

// ---- state init: copy h0,c0 (fp32) into ws state buffers -------------------
__global__ void init_state(const float* __restrict__ h0, const float* __restrict__ c0,
                           float* __restrict__ hs, float* __restrict__ cs){
  int i = blockIdx.x*256 + threadIdx.x;   // grid 512*256 = 131072 exact
  hs[i] = h0[i];
  cs[i] = c0[i];
}

// ---- pack kernel weights [128,1024] -> B-fragment order --------------------
// kp[((nt*4+ks)*64 + l)*8 + i] = K[32ks + 8*(l>>4) + i][16nt + (l&15)]
__global__ void pack_K(const float* __restrict__ K, unsigned short* __restrict__ kp){
  int tg = blockIdx.x*256 + threadIdx.x;  // < 64*4*64 = 16384
  int nt = tg >> 8; int ks = (tg >> 6) & 3; int l = tg & 63;
  int g = l >> 4, c = l & 15;
  short8 o;
  #pragma unroll
  for (int i = 0; i < 8; ++i)
    o[i] = (short)f2bf(K[(size_t)(32*ks + 8*g + i)*NU + 16*nt + c]);
  *(short8*)&kp[((size_t)(nt*4 + ks)*64 + l)*8] = o;
}

// ---- pack recurrent kernel [256,1024] -> B-fragment order ------------------
__global__ void pack_R(const float* __restrict__ R, unsigned short* __restrict__ Rp){
  int tg = blockIdx.x*256 + threadIdx.x;  // < 64*8*64 = 32768
  int nt = tg >> 9; int ks = (tg >> 6) & 7; int l = tg & 63;
  int g = l >> 4, c = l & 15;
  short8 o;
  #pragma unroll
  for (int i = 0; i < 8; ++i)
    o[i] = (short)f2bf(R[(size_t)(32*ks + 8*g + i)*NU + 16*nt + c]);
  *(short8*)&Rp[((size_t)(nt*8 + ks)*64 + l)*8] = o;
}

// ---- pack x chunk -> A-fragment order (bf16) -------------------------------
// xp[((m*4+ks)*64 + l)*8 + i] = x[16rb + (l&15)][t0+tl][32ks + 8*(l>>4) + i]
// m = rb*Tc + tl
__global__ void pack_x(const float* __restrict__ x, unsigned short* __restrict__ xp,
                       int t0, int Tc){
  int tl = blockIdx.x, rb = blockIdx.y;
  int tid = threadIdx.x;
  int r = tid >> 4, kk = tid & 15;
  int b = rb*16 + r, t = t0 + tl;
  const float* s = &x[((size_t)b*T_ + t)*F_ + kk*8];
  float4 v0 = *(const float4*)s;
  float4 v1 = *(const float4*)(s + 4);
  int ks = kk >> 2, g = kk & 3, l = g*16 + r;
  int m = rb*Tc + tl;
  short8 o;
  o[0]=(short)f2bf(v0.x); o[1]=(short)f2bf(v0.y); o[2]=(short)f2bf(v0.z); o[3]=(short)f2bf(v0.w);
  o[4]=(short)f2bf(v1.x); o[5]=(short)f2bf(v1.y); o[6]=(short)f2bf(v1.z); o[7]=(short)f2bf(v1.w);
  *(short8*)&xp[((size_t)(m*4 + ks)*64 + l)*8] = o;
}

// ---- phase 1: xk = x@K + bias, written in D-fragment order (bf16) ----------
// block = 4 waves, each wave does 2 m-tiles over all 64 n-tiles, K=128 (4 ks)
__global__ __launch_bounds__(256) void gemm_xk(const unsigned short* __restrict__ xp,
        const unsigned short* __restrict__ kp, const float* __restrict__ bias,
        unsigned short* __restrict__ xkp){
  int w = threadIdx.x >> 6, l = threadIdx.x & 63;
  int c = l & 15;
  int m0 = blockIdx.x*8 + w*2;
  short8 a0[4], a1[4];
  #pragma unroll
  for (int ks = 0; ks < 4; ++ks){
    a0[ks] = *(const short8*)&xp[((size_t)(m0*4 + ks)*64 + l)*8];
    a1[ks] = *(const short8*)&xp[((size_t)((m0+1)*4 + ks)*64 + l)*8];
  }
  #pragma unroll 4
  for (int nt = 0; nt < 64; ++nt){
    short8 kf[4];
    #pragma unroll
    for (int ks = 0; ks < 4; ++ks)
      kf[ks] = *(const short8*)&kp[((size_t)(nt*4 + ks)*64 + l)*8];
    float bs = bias[nt*16 + c];
    f32x4 A = {0.f,0.f,0.f,0.f}, Bc = {0.f,0.f,0.f,0.f};
    #pragma unroll
    for (int ks = 0; ks < 4; ++ks){
      A  = __builtin_amdgcn_mfma_f32_16x16x32_bf16(a0[ks], kf[ks], A,  0, 0, 0);
      Bc = __builtin_amdgcn_mfma_f32_16x16x32_bf16(a1[ks], kf[ks], Bc, 0, 0, 0);
    }
    us4 o0, o1;
    #pragma unroll
    for (int r = 0; r < 4; ++r){ o0[r] = f2bf(A[r] + bs); o1[r] = f2bf(Bc[r] + bs); }
    *(us4*)&xkp[((size_t)(m0*64 + nt)*64 + l)*4]     = o0;
    *(us4*)&xkp[((size_t)((m0+1)*64 + nt)*64 + l)*4] = o1;
  }
}

// ---- phase 2: the sequential scan ------------------------------------------
// 32 blocks (16 batch rows each) x 512 threads (8 waves).
// wave w owns u-slice [32w, 32w+32): n-tiles nt = 16q + 2w + j (q=gate, j=0,1)
__global__ __launch_bounds__(512, 2) void lstm_scan(const unsigned short* __restrict__ Rp,
        const unsigned short* __restrict__ xkp, float* __restrict__ hstate,
        float* __restrict__ cstate, float* __restrict__ out, int Tc, int last){
  int rb = blockIdx.x;
  int tid = threadIdx.x;
  int w = tid >> 6, l = tid & 63, g = l >> 4, c = l & 15;
  __shared__ unsigned short hl[2][16][264];   // [buf][row][k], +8 pad
  {
    int row = tid >> 5, k0 = (tid & 31)*8;
    const float* hp = &hstate[(size_t)(rb*16 + row)*U_ + k0];
    float4 v0 = *(const float4*)hp;
    float4 v1 = *(const float4*)(hp + 4);
    unsigned short* d = &hl[0][row][k0];
    d[0]=f2bf(v0.x); d[1]=f2bf(v0.y); d[2]=f2bf(v0.z); d[3]=f2bf(v0.w);
    d[4]=f2bf(v1.x); d[5]=f2bf(v1.y); d[6]=f2bf(v1.z); d[7]=f2bf(v1.w);
  }
  float creg[2][4], hreg[2][4];
  #pragma unroll
  for (int j = 0; j < 2; ++j)
    #pragma unroll
    for (int r = 0; r < 4; ++r)
      creg[j][r] = cstate[(size_t)(rb*16 + 4*g + r)*U_ + w*32 + j*16 + c];
  __syncthreads();

  int buf = 0;
  for (int t = 0; t < Tc; ++t){
    // A-fragments: h from LDS (row = c = l&15, k = 32ks + 8g + i)
    short8 af[8];
    #pragma unroll
    for (int ks = 0; ks < 8; ++ks)
      af[ks] = *(const short8*)&hl[buf][c][ks*32 + g*8];
    // xk fragments for this timestep (D-fragment order, coalesced 8B/lane)
    size_t m64 = ((size_t)rb*Tc + t)*64;
    us4 xkf[8];
    #pragma unroll
    for (int idx = 0; idx < 8; ++idx){
      int nt = (idx >> 1)*16 + w*2 + (idx & 1);
      xkf[idx] = *(const us4*)&xkp[((m64 + nt)*64 + l)*4];
    }
    // z = h @ R, streaming R B-fragments from L2, double-buffered
    short8 bcur[8], bnxt[8];
    #pragma unroll
    for (int ks = 0; ks < 8; ++ks)
      bcur[ks] = *(const short8*)&Rp[((size_t)((w*2)*8 + ks)*64 + l)*8];
    f32x4 z[8];
    #pragma unroll
    for (int idx = 0; idx < 8; ++idx){
      if (idx < 7){
        int ntn = ((idx+1) >> 1)*16 + w*2 + ((idx+1) & 1);
        #pragma unroll
        for (int ks = 0; ks < 8; ++ks)
          bnxt[ks] = *(const short8*)&Rp[((size_t)(ntn*8 + ks)*64 + l)*8];
      }
      f32x4 a = {0.f,0.f,0.f,0.f};
      #pragma unroll
      for (int ks = 0; ks < 8; ++ks)
        a = __builtin_amdgcn_mfma_f32_16x16x32_bf16(af[ks], bcur[ks], a, 0, 0, 0);
      z[idx] = a;
      if (idx < 7){
        #pragma unroll
        for (int ks = 0; ks < 8; ++ks) bcur[ks] = bnxt[ks];
      }
    }
    // gates + state update (fp32). idx = 2q + j; q: 0=i,1=f,2=o,3=g
    #pragma unroll
    for (int j = 0; j < 2; ++j){
      #pragma unroll
      for (int r = 0; r < 4; ++r){
        float zi = z[0+j][r] + bf2f(xkf[0+j][r]);
        float zf = z[2+j][r] + bf2f(xkf[2+j][r]);
        float zo = z[4+j][r] + bf2f(xkf[4+j][r]);
        float zg = z[6+j][r] + bf2f(xkf[6+j][r]);
        float ii = sigm(zi), ff = sigm(zf), oo = sigm(zo), gg = tanh_f(zg);
        float cn = ff*creg[j][r] + ii*gg;
        creg[j][r] = cn;
        float hh = oo*tanh_f(cn);
        hreg[j][r] = hh;
        // write h_t (bf16) to the other LDS buffer: row = 4g + r, col = u
        hl[buf ^ 1][4*g + r][w*32 + j*16 + c] = f2bf(hh);
      }
    }
    __syncthreads();
    buf ^= 1;
  }
  // persist state; emit output on last chunk
  #pragma unroll
  for (int j = 0; j < 2; ++j)
    #pragma unroll
    for (int r = 0; r < 4; ++r){
      size_t o = (size_t)(rb*16 + 4*g + r)*U_ + w*32 + j*16 + c;
      hstate[o] = hreg[j][r];
      cstate[o] = creg[j][r];
      if (last) out[o] = hreg[j][r];
    }
}

extern "C" void kernel_launch(void* const* d_in, const int* in_sizes, int n_in,
                              void* d_out, int out_size, void* d_ws, size_t ws_size,
                              hipStream_t stream){
  const float* x    = (const float*)d_in[0];
  const float* K    = (const float*)d_in[1];
  const float* R    = (const float*)d_in[2];
  const float* bias = (const float*)d_in[3];
  const float* h0   = (const float*)d_in[4];
  const float* c0   = (const float*)d_in[5];
  float* out = (float*)d_out;

  size_t off = 0;
  char* base = (char*)d_ws;
  float* hstate = (float*)(base + off); off += 524288;           // 512*256*4
  float* cstate = (float*)(base + off); off += 524288;
  unsigned short* kp = (unsigned short*)(base + off); off += 262144;  // 128*1024*2
  unsigned short* Rp = (unsigned short*)(base + off); off += 524288;  // 256*1024*2

  // choose time-chunk so xpack+xkpack fit in remaining workspace
  int Tc = 1024;
  while (Tc > 8 && off + (size_t)Tc*(131072 + 1048576) > ws_size) Tc >>= 1;
  unsigned short* xp  = (unsigned short*)(base + off); off += (size_t)131072*Tc;
  unsigned short* xkp = (unsigned short*)(base + off);

  init_state<<<dim3(512), dim3(256), 0, stream>>>(h0, c0, hstate, cstate);
  pack_K<<<dim3(64),  dim3(256), 0, stream>>>(K, kp);
  pack_R<<<dim3(128), dim3(256), 0, stream>>>(R, Rp);

  int nch = 1024 / Tc;
  for (int ch = 0; ch < nch; ++ch){
    int t0 = ch*Tc;
    pack_x<<<dim3(Tc, 32), dim3(256), 0, stream>>>(x, xp, t0, Tc);
    gemm_xk<<<dim3(Tc*4), dim3(256), 0, stream>>>(xp, kp, bias, xkp);
    lstm_scan<<<dim3(32), dim3(512), 0, stream>>>(Rp, xkp, hstate, cstate, out,
                                                  Tc, (ch == nch - 1) ? 1 : 0);
  }
}